// Round 6
// baseline (661.040 us; speedup 1.0000x reference)
//
#include <hip/hip_runtime.h>
#include <hip/hip_fp16.h>
#include <math.h>

#define N_LEVELS 16
#define LOG2_T 19
#define TABLE_SIZE (1 << LOG2_T)
#define IDX_MASK ((unsigned)(TABLE_SIZE - 1))
#define N_STAGED 4                  // dense-precomputed coarse levels 0..3
#define N_FINE (N_LEVELS - N_STAGED)
#define DENSE_CAP 11936             // padded dense entries (4B each)
#define N_LDS 2728                  // L0(1000)+L1(1728) staged in LDS (10.9 KB)
#define THREADS 256
#define ITERS 16
#define PTS_PER_BLOCK (32 * ITERS)  // 8 lanes per point -> 32 pts per iter

typedef float f2_t __attribute__((ext_vector_type(2)));
typedef float f4_t __attribute__((ext_vector_type(4)));

struct Params {
    float res[N_LEVELS];
    int   c0[N_STAGED];
    int   K[N_STAGED];
    int   K2[N_STAGED];
    int   base[N_STAGED + 1];   // 4-entry-padded prefix offsets
    int   n_pts;
};

// ---- pass 1a: fp16-compress the 12 fine tables into workspace.
__global__ __launch_bounds__(256) void convert_fine(
    const f2_t* __restrict__ emb, unsigned* __restrict__ tab, int n)
{
    int i = blockIdx.x * 256 + threadIdx.x;
    if (i >= n) return;
    f2_t e = __builtin_nontemporal_load(&emb[(size_t)N_STAGED * TABLE_SIZE + i]);
    union { __half2 h2; unsigned u; } c;
    c.h2 = __floats2half2_rn(e.x, e.y);
    __builtin_nontemporal_store(c.u, &tab[i]);
}

// ---- pass 1b: dense re-indexed coarse tables (L0..L3), fp16.
__global__ __launch_bounds__(256) void build_dense(
    const f2_t* __restrict__ emb, unsigned* __restrict__ dense, Params P)
{
    int t = blockIdx.x * 256 + threadIdx.x;
    if (t >= P.base[N_STAGED]) return;
    int lev = 3;
    if (t < P.base[3]) lev = 2;
    if (t < P.base[2]) lev = 1;
    if (t < P.base[1]) lev = 0;
    int li = t - P.base[lev];
    int K  = P.K[lev];
    if (li >= K * K * K) return;               // padding slot
    int kx = li % K; int r2 = li / K; int ky = r2 % K; int kz = r2 / K;
    unsigned cx = (unsigned)(P.c0[lev] + kx);
    unsigned cy = (unsigned)(P.c0[lev] + ky);
    unsigned cz = (unsigned)(P.c0[lev] + kz);
    unsigned h = (cx ^ (cy * 2654435761u) ^ (cz * 805459861u)) & IDX_MASK;
    f2_t e = emb[(size_t)lev * TABLE_SIZE + h];
    union { __half2 h2; unsigned u; } c;
    c.h2 = __floats2half2_rn(e.x, e.y);
    dense[t] = c.u;
}

__device__ __forceinline__ void acc_corner(
    unsigned w0, unsigned w1, float g0, float g1, float& a0, float& a1)
{
    union { unsigned u; __half2 h; } p0, p1;
    p0.u = w0; p1.u = w1;
    a0 += g0 * __low2float(p0.h)  + g1 * __low2float(p1.h);
    a1 += g0 * __high2float(p0.h) + g1 * __high2float(p1.h);
}

__device__ __forceinline__ unsigned pick4(uint4 g, unsigned s)
{
    unsigned t0 = (s & 1u) ? g.y : g.x;
    unsigned t1 = (s & 1u) ? g.w : g.z;
    return (s & 2u) ? t1 : t0;
}

// Weight setup shared by all paths: EXACT fp32 op sequence of the verified
// baseline (add, div, floor -- no FMA contraction of the vmin term).
#define GRID_SETUP(gridv)                                                  \
    float tx = (xx + 1.0f) / (gridv);                                      \
    float ty = (xy + 1.0f) / (gridv);                                      \
    float tz = (xz + 1.0f) / (gridv);                                      \
    int blx = (int)floorf(tx);                                             \
    int bly = (int)floorf(ty);                                             \
    int blz = (int)floorf(tz);                                             \
    float wx = (xx - ((float)blx * (gridv) + -1.0f)) / (gridv);            \
    float wy = (xy - ((float)bly * (gridv) + -1.0f)) / (gridv);            \
    float wz = (xz - ((float)blz * (gridv) + -1.0f)) / (gridv);            \
    float fy[2] = {1.0f - wy, wy};                                         \
    float fz[2] = {1.0f - wz, wz};                                         \
    float fx0 = 1.0f - wx, fx1 = wx;

// Fine level: hashed fp16 table, mod-4 16B group gathers (x-prime==1 =>
// i0,i1 share the aligned 4-group unless blx%4==3; ~25% patch rate).
__device__ __forceinline__ void eval_fine(
    float grid, const unsigned* __restrict__ tab,
    float xx, float xy, float xz, float& a0, float& a1)
{
    GRID_SETUP(grid)
    unsigned ux  = (unsigned)blx;
    unsigned hy0 = (unsigned)bly * 2654435761u;
    unsigned hy1 = ((unsigned)bly + 1u) * 2654435761u;
    unsigned hz0 = (unsigned)blz * 805459861u;
    unsigned hz1 = ((unsigned)blz + 1u) * 805459861u;
    unsigned w0a[4], w1a[4], i1a[4];
#pragma unroll
    for (int yz = 0; yz < 4; ++yz) {
        unsigned hyz = ((yz & 2) ? hy1 : hy0) ^ ((yz & 1) ? hz1 : hz0);
        unsigned i0 = (ux ^ hyz) & IDX_MASK;
        unsigned i1 = ((ux + 1u) ^ hyz) & IDX_MASK;
        i1a[yz] = i1;
        uint4 g = *(const uint4*)(tab + (i0 & ~3u));   // 16B aligned
        w0a[yz] = pick4(g, i0 & 3u);
        w1a[yz] = pick4(g, i1 & 3u);                   // bogus iff ux%4==3
    }
    if ((ux & 3u) == 3u) {
#pragma unroll
        for (int yz = 0; yz < 4; ++yz) w1a[yz] = tab[i1a[yz]];
    }
    a0 = 0.0f; a1 = 0.0f;
#pragma unroll
    for (int yz = 0; yz < 4; ++yz) {
        float wyz = fy[yz >> 1] * fz[yz & 1];
        acc_corner(w0a[yz], w1a[yz], fx0 * wyz, fx1 * wyz, a0, a1);
    }
}

// Coarse level LEV: dense re-indexed table, from LDS (L0,L1) or global
// (L2,L3). Dense layout => x-neighbor is idx+1; 16B groups, patch iff idx%4==3.
template <int LEV, bool FROM_LDS>
__device__ __forceinline__ void eval_coarse(
    const Params& P, const unsigned* s_dense, const unsigned* __restrict__ denseG,
    const f2_t* __restrict__ emb,
    float xx, float xy, float xz, float& a0, float& a1)
{
    float grid = 2.0f / P.res[LEV];
    GRID_SETUP(grid)
    int K = P.K[LEV], K2 = P.K2[LEV];
    int kx = blx - P.c0[LEV], ky = bly - P.c0[LEV], kz = blz - P.c0[LEV];
    a0 = 0.0f; a1 = 0.0f;
    unsigned lim = (unsigned)(K - 1);
    if ((unsigned)kx < lim && (unsigned)ky < lim && (unsigned)kz < lim) {
        int i00 = (kz * K + ky) * K + kx;
        if (FROM_LDS) {
            int ib = P.base[LEV] + i00;
#pragma unroll
            for (int yz = 0; yz < 4; ++yz) {
                int id = ib + (yz >> 1) * K + (yz & 1) * K2;
                float wyz = fy[yz >> 1] * fz[yz & 1];
                acc_corner(s_dense[id], s_dense[id + 1], fx0 * wyz, fx1 * wyz,
                           a0, a1);
            }
        } else {
            const unsigned* tb = denseG + P.base[LEV];   // base % 4 == 0
#pragma unroll
            for (int yz = 0; yz < 4; ++yz) {
                unsigned id = (unsigned)(i00 + (yz >> 1) * K + (yz & 1) * K2);
                uint4 g = *(const uint4*)(tb + (id & ~3u));
                unsigned s0 = id & 3u;
                unsigned w0 = pick4(g, s0);
                unsigned w1;
                if (s0 == 3u) w1 = tb[id + 1u];          // ~25% straddle patch
                else          w1 = pick4(g, s0 + 1u);
                float wyz = fy[yz >> 1] * fz[yz & 1];
                acc_corner(w0, w1, fx0 * wyz, fx1 * wyz, a0, a1);
            }
        }
    } else {
        // cold safety fallback: exact f32 hash gathers (corner outside box)
        const f2_t* tab = emb + (size_t)LEV * TABLE_SIZE;
#pragma unroll
        for (int k = 0; k < 8; ++k) {
            int bx = (k >> 2) & 1, by = (k >> 1) & 1, bz = k & 1;
            unsigned h = ((unsigned)(blx + bx)
                          ^ ((unsigned)(bly + by) * 2654435761u)
                          ^ ((unsigned)(blz + bz) * 805459861u)) & IDX_MASK;
            f2_t e = tab[h];
            float w = (bx ? wx : 1.0f - wx) * fy[by] * fz[bz];
            a0 += w * e.x; a1 += w * e.y;
        }
    }
}

// ---- pass 2: thread t = (point t>>3, level-pair t&7).
// Stores are consecutive 16B across lanes -> fully coalesced; 8 lanes share
// each point's x (same-address merge); per-lane level constants hoisted.
__global__ __launch_bounds__(256) void ingp_hash_v5(
    const float* __restrict__ x,
    const unsigned* __restrict__ tabF,
    const unsigned* __restrict__ denseG,
    const f2_t* __restrict__ emb,
    float* __restrict__ out,
    Params P)
{
    __shared__ __align__(16) unsigned s_dense[N_LDS];
    __shared__ float s_res[N_LEVELS];
    {
        const uint4* src = (const uint4*)denseG;       // L0,L1 = dense[0..N_LDS)
        uint4* dst = (uint4*)s_dense;
        for (int id = threadIdx.x; id < N_LDS / 4; id += THREADS) dst[id] = src[id];
        if (threadIdx.x < N_LEVELS) s_res[threadIdx.x] = P.res[threadIdx.x];
    }
    __syncthreads();

    int lp  = threadIdx.x & 7;
    int ptl = threadIdx.x >> 3;

    // hoisted per-lane fine-level constants (levels are lane-fixed)
    float gridA = 2.0f / s_res[2 * lp];
    float gridB = 2.0f / s_res[2 * lp + 1];
    int fo = 2 * lp - 4; if (fo < 0) fo = 0;
    const unsigned* tA = tabF + (size_t)fo * TABLE_SIZE;
    const unsigned* tB = tabF + (size_t)(fo + 1) * TABLE_SIZE;

    int base_n = blockIdx.x * PTS_PER_BLOCK + ptl;

#pragma unroll 1
    for (int it = 0; it < ITERS; ++it) {
        int n = base_n + it * 32;
        int nc = n < P.n_pts ? n : P.n_pts - 1;
        float xx = fminf(fmaxf(__builtin_nontemporal_load(&x[nc * 3 + 0]), -1.0f), 1.0f);
        float xy = fminf(fmaxf(__builtin_nontemporal_load(&x[nc * 3 + 1]), -1.0f), 1.0f);
        float xz = fminf(fmaxf(__builtin_nontemporal_load(&x[nc * 3 + 2]), -1.0f), 1.0f);

        float r0, r1, r2, r3;    // scalars: f4_t elements can't bind to float&
        if (lp == 0) {
            eval_coarse<0, true>(P, s_dense, denseG, emb, xx, xy, xz, r0, r1);
            eval_coarse<1, true>(P, s_dense, denseG, emb, xx, xy, xz, r2, r3);
        } else if (lp == 1) {
            eval_coarse<2, false>(P, s_dense, denseG, emb, xx, xy, xz, r0, r1);
            eval_coarse<3, false>(P, s_dense, denseG, emb, xx, xy, xz, r2, r3);
        } else {
            eval_fine(gridA, tA, xx, xy, xz, r0, r1);
            eval_fine(gridB, tB, xx, xy, xz, r2, r3);
        }

        if (n < P.n_pts) {
            f4_t o4 = {r0, r1, r2, r3};
            __builtin_nontemporal_store(
                o4, (f4_t*)(out + (size_t)n * (N_LEVELS * 2) + lp * 4));
        }
    }
}

// ---- fallback (ws unavailable): round-3 proven f32 pair kernel.
__global__ __launch_bounds__(256) void ingp_hash_pair_f32(
    const float* __restrict__ x, const f2_t* __restrict__ emb,
    float* __restrict__ out, Params P)
{
    int b = blockIdx.x;
    int slot = b & 7;
    int n = (b >> 3) * 256 + (int)threadIdx.x;
    if (n >= P.n_pts) return;
    float xx = fminf(fmaxf(x[n * 3 + 0], -1.0f), 1.0f);
    float xy = fminf(fmaxf(x[n * 3 + 1], -1.0f), 1.0f);
    float xz = fminf(fmaxf(x[n * 3 + 2], -1.0f), 1.0f);
    float r0 = 0.f, r1 = 0.f, r2 = 0.f, r3 = 0.f;
#pragma unroll
    for (int hl = 0; hl < 2; ++hl) {
        int lev = 2 * slot + hl;
        float grid = 2.0f / P.res[lev];
        int blx = (int)floorf((xx + 1.0f) / grid);
        int bly = (int)floorf((xy + 1.0f) / grid);
        int blz = (int)floorf((xz + 1.0f) / grid);
        float wx = (xx - ((float)blx * grid + -1.0f)) / grid;
        float wy = (xy - ((float)bly * grid + -1.0f)) / grid;
        float wz = (xz - ((float)blz * grid + -1.0f)) / grid;
        const f2_t* tab = emb + (size_t)lev * TABLE_SIZE;
        float acc0 = 0.0f, acc1 = 0.0f;
#pragma unroll
        for (int k = 0; k < 8; ++k) {
            int bx = (k >> 2) & 1, by = (k >> 1) & 1, bz = k & 1;
            unsigned h = ((unsigned)(blx + bx)
                          ^ ((unsigned)(bly + by) * 2654435761u)
                          ^ ((unsigned)(blz + bz) * 805459861u)) & IDX_MASK;
            f2_t e = tab[h];
            float w = (bx ? wx : 1.0f - wx) * (by ? wy : 1.0f - wy) * (bz ? wz : 1.0f - wz);
            acc0 += w * e.x; acc1 += w * e.y;
        }
        if (hl == 0) { r0 = acc0; r1 = acc1; } else { r2 = acc0; r3 = acc1; }
    }
    f4_t o4 = {r0, r1, r2, r3};
    __builtin_nontemporal_store(o4, (f4_t*)(out + (size_t)n * (N_LEVELS * 2) + slot * 4));
}

extern "C" void kernel_launch(void* const* d_in, const int* in_sizes, int n_in,
                              void* d_out, int out_size, void* d_ws, size_t ws_size,
                              hipStream_t stream) {
    const float* x   = (const float*)d_in[0];
    const float* emb = (const float*)d_in[1];
    float* out = (float*)d_out;
    int n_pts = in_sizes[0] / 3;

    Params P;
    double b = exp((log(512.0) - log(16.0)) / 15.0);
    for (int i = 0; i < N_LEVELS; ++i)
        P.res[i] = (float)floor(16.0 * pow(b, (double)i));
    P.n_pts = n_pts;

    // Dense box bounds (same fp32 ops the device uses; x in [0,1] after clip).
    int base = 0;
    for (int l = 0; l < N_STAGED; ++l) {
        float grid = 2.0f / P.res[l];
        int blmin = (int)floorf(1.0f / grid);
        int blmax = (int)floorf(2.0f / grid);
        int K = blmax - blmin + 2;
        P.c0[l] = blmin; P.K[l] = K; P.K2[l] = K * K;
        P.base[l] = base;
        base += K * K * K;
        base = (base + 3) & ~3;        // 4-entry align each segment (16B loads)
    }
    P.base[N_STAGED] = base;

    size_t need = (size_t)N_FINE * TABLE_SIZE * 4 + (size_t)DENSE_CAP * 4;
    bool ok = (base <= DENSE_CAP) && (P.base[2] == N_LDS) &&
              (ws_size >= need) && (d_ws != nullptr);
    if (ok) {
        unsigned* tabF   = (unsigned*)d_ws;
        unsigned* denseG = tabF + (size_t)N_FINE * TABLE_SIZE;
        int nF = N_FINE * TABLE_SIZE;
        hipLaunchKernelGGL(convert_fine, dim3((nF + 255) / 256), dim3(256), 0, stream,
                           (const f2_t*)emb, tabF, nF);
        hipLaunchKernelGGL(build_dense, dim3((base + 255) / 256), dim3(256), 0, stream,
                           (const f2_t*)emb, denseG, P);
        int blocks = (n_pts + PTS_PER_BLOCK - 1) / PTS_PER_BLOCK;
        hipLaunchKernelGGL(ingp_hash_v5, dim3(blocks), dim3(256), 0, stream,
                           x, tabF, denseG, (const f2_t*)emb, out, P);
    } else {
        int blocks = 8 * ((n_pts + 255) / 256);
        hipLaunchKernelGGL(ingp_hash_pair_f32, dim3(blocks), dim3(256), 0, stream,
                           x, (const f2_t*)emb, out, P);
    }
}